// Round 1
// baseline (142.457 us; speedup 1.0000x reference)
//
#include <hip/hip_runtime.h>
#include <math.h>

#define HID 64
#define KB 9            // NUM_BINS - 1
#define NB 10
#define NTOT (128 * 20000)
#define BLOCK 256
#define EPB 2048        // elements per block (main kernel)
#define CHUNK 512       // elements per single-pass output chunk
#define NCHUNK (EPB / CHUNK)
#define FEPT 2          // fallback kernel elements/thread
#define LEAKY 0.01f
#define RSTRIDE 20      // floats per region row (9 A + 9 C + 2 pad) = 5 f4s
#define SENT 3.0e38f
#define LOG2E 1.44269504088896f

// bucket LUT for region search
#define NBUK 2048
#define BLO (-6.0f)
#define BSCALE (2048.0f / 12.0f)

#define TAB_U32 (128 + 65 * RSTRIDE)      // 1428 u32: 128 thresholds + 65 rows
#define WS_U32 (TAB_U32 + NBUK / 4)       // + 512 u32 of u8 buckets = 1940 (= 485 f4)
#define WS_BYTES (WS_U32 * 4)

typedef float v4f __attribute__((ext_vector_type(4)));
typedef float v2f __attribute__((ext_vector_type(2)));

// ---------------- setup: 97 blocks x 64 threads (unchanged) ----------------
__global__ __launch_bounds__(64) void setup_kernel(
    const float* __restrict__ W1, const float* __restrict__ b1,
    const float* __restrict__ W2, const float* __restrict__ b2,
    float* __restrict__ ws)
{
    __shared__ float t_lds[HID], w_lds[HID], b_lds[HID], tsrt[HID];
    __shared__ float w2_lds[HID * KB];
    __shared__ float red[18 * 65];   // rows padded to 65 -> conflict-free reduce

    const int j = threadIdx.x;       // unit index (original order)
    const int blk = blockIdx.x;
    const float w = W1[j], b = b1[j];
    const float t = (w != 0.0f) ? (-b / w) : -SENT;  // w==0: constant sign, park at -inf
    t_lds[j] = t; w_lds[j] = w; b_lds[j] = b;
    if (blk < 65) {
        #pragma unroll
        for (int q = j; q < HID * KB; q += 64) w2_lds[q] = W2[q];
    }
    __syncthreads();

    int rank = 0;                    // rank sort (unique ranks via index tiebreak)
    for (int i = 0; i < HID; ++i) {
        float ti = t_lds[i];
        rank += (ti < t || (ti == t && i < j)) ? 1 : 0;
    }
    tsrt[rank] = t;
    __syncthreads();

    if (blk >= 65) {                 // bucket fill
        const int bb = (blk - 65) * 64 + j;
        const float edge = BLO + ((float)bb - 0.5f) * (1.0f / BSCALE);  // half-bucket margin
        int cnt = 0;
        for (int i = 0; i < HID; ++i) cnt += (tsrt[i] <= edge) ? 1 : 0;
        ((unsigned char*)(ws + TAB_U32))[bb] = (bb == 0) ? 0 : (unsigned char)cnt;
        return;
    }

    const int r = blk;               // region index 0..64
    float xm;                        // point strictly inside region r
    if (r == 0)        xm = tsrt[0] - 1.0f;
    else if (r == HID) xm = tsrt[HID - 1] + 1.0f;
    else               xm = 0.5f * (tsrt[r - 1] + tsrt[r]);

    const float s = (fmaf(w, xm, b) >= 0.0f) ? 1.0f : LEAKY;
    #pragma unroll
    for (int k = 0; k < KB; ++k) {
        const float w2s = w2_lds[j * KB + k] * s;
        red[(2 * k) * 65 + j]     = w2s * w;   // A contribution
        red[(2 * k + 1) * 65 + j] = w2s * b;   // C contribution
    }
    __syncthreads();

    if (j < 18) {   // threads 0..17 each sum one row of 64 (deterministic order)
        float acc = 0.0f;
        for (int i = 0; i < HID; ++i) acc += red[j * 65 + i];
        const int k = j >> 1;
        if (j & 1) ws[128 + r * RSTRIDE + KB + k] = (acc + b2[k]) * LOG2E;  // C'
        else       ws[128 + r * RSTRIDE + k]      = acc * LOG2E;            // A'
    }
    if (r == 0) { ws[j] = tsrt[j]; ws[64 + j] = SENT; }
}

// ---------------- main: single-pass merged output via LDS tile ----------------
// Each thread owns 8 CONSECUTIVE elements -> compacted nonzero list is globally
// sorted, so per-chunk sublists are contiguous (3 binary searches for bounds).
// Per 512-element chunk: softmax-scatter nonzeros into a 20 KB LDS tile, then
// stream the tile out as full-line coalesced nontemporal f4 stores, merging the
// zero-element default pattern at read time (tile garbage selected away via xs).
// Every output line is written to HBM exactly once: no WAW, no RMW refetch.
__global__ __launch_bounds__(BLOCK) void main_kernel(
    const float* __restrict__ expr, const float* __restrict__ ws,
    float* __restrict__ out)
{
    __shared__ __align__(16) unsigned int sdata[WS_U32];   // ts | tab | buckets
    __shared__ __align__(16) float xs[EPB];
    __shared__ __align__(16) float tile[CHUNK * NB];       // 20 KB merge tile
    __shared__ unsigned short list[EPB];
    __shared__ int swsum[4];
    __shared__ int bnd[NCHUNK];                            // [1..NCHUNK-1] used

    const int tid = threadIdx.x;
    const int lane = tid & 63, wv = tid >> 6;

    // stage tables once per block
    #pragma unroll
    for (int t = tid; t < WS_U32 / 4; t += BLOCK)
        ((v4f*)sdata)[t] = ((const v4f*)ws)[t];

    // block's 2048 expr floats: thread owns elements 8*tid .. 8*tid+7
    const size_t e0 = (size_t)blockIdx.x * EPB;
    const v4f xa = ((const v4f*)(expr + e0))[2 * tid];
    const v4f xb = ((const v4f*)(expr + e0))[2 * tid + 1];
    ((v4f*)xs)[2 * tid] = xa;
    ((v4f*)xs)[2 * tid + 1] = xb;
    const float xr[8] = {xa.x, xa.y, xa.z, xa.w, xb.x, xb.y, xb.z, xb.w};

    int cnt = 0;
    #pragma unroll
    for (int j = 0; j < 8; ++j) cnt += (xr[j] != 0.0f) ? 1 : 0;

    // wave-inclusive scan of per-thread counts
    int incl = cnt;
    #pragma unroll
    for (int d = 1; d < 64; d <<= 1) {
        int n = __shfl_up(incl, d, 64);
        if (lane >= d) incl += n;
    }
    if (lane == 63) swsum[wv] = incl;

    // mask output: element-coalesced nontemporal f4 stores (zero reuse)
    float* mout = out + (size_t)NTOT * NB + e0;
    const v4f ma = {xr[0] != 0.f ? 1.f : 0.f, xr[1] != 0.f ? 1.f : 0.f,
                    xr[2] != 0.f ? 1.f : 0.f, xr[3] != 0.f ? 1.f : 0.f};
    const v4f mb = {xr[4] != 0.f ? 1.f : 0.f, xr[5] != 0.f ? 1.f : 0.f,
                    xr[6] != 0.f ? 1.f : 0.f, xr[7] != 0.f ? 1.f : 0.f};
    __builtin_nontemporal_store(ma, ((v4f*)mout) + 2 * tid);
    __builtin_nontemporal_store(mb, ((v4f*)mout) + 2 * tid + 1);

    __syncthreads();                 // xs + swsum visible

    const int s0 = swsum[0], s1 = swsum[1], s2 = swsum[2], s3 = swsum[3];
    const int total = s0 + s1 + s2 + s3;
    int base = (incl - cnt) + (wv > 0 ? s0 : 0) + (wv > 1 ? s1 : 0) + (wv > 2 ? s2 : 0);

    #pragma unroll
    for (int j = 0; j < 8; ++j) {
        if (xr[j] != 0.0f) list[base++] = (unsigned short)(8 * tid + j);
    }

    __syncthreads();                 // list complete (globally ascending)

    // chunk boundary search: bnd[c] = first list index with element >= c*CHUNK
    if (tid < NCHUNK - 1) {
        const int target = (tid + 1) * CHUNK;
        int lo = 0, hi = total;
        while (lo < hi) {
            const int mid = (lo + hi) >> 1;
            if ((int)list[mid] < target) lo = mid + 1; else hi = mid;
        }
        bnd[tid + 1] = lo;
    }
    __syncthreads();                 // bnd visible

    const float* ts  = (const float*)sdata;
    const float* tab = (const float*)sdata + 128;
    const unsigned char* buk = (const unsigned char*)(sdata + TAB_U32);
    float* gout = out + e0 * NB;

    for (int ch = 0; ch < NCHUNK; ++ch) {
        const int lo = (ch == 0) ? 0 : bnd[ch];
        const int hi = (ch == NCHUNK - 1) ? total : bnd[ch + 1];

        // scatter: softmax for this chunk's nonzeros -> LDS tile (8B LDS stores)
        for (int i = lo + tid; i < hi; i += BLOCK) {
            const int e = list[i];
            const float xe = xs[e];
            // bucket start (guaranteed <= region(xe)), then exact forward scan
            const float fb = fminf(2047.0f, fmaxf(0.0f, (xe - BLO) * BSCALE));
            int idx = buk[(int)fb];
            while (ts[idx] <= xe) ++idx;   // ts padded with SENT -> terminates
            const v4f* rowv = (const v4f*)(tab + idx * RSTRIDE);
            const v4f r0 = rowv[0], r1 = rowv[1], r2 = rowv[2], r3 = rowv[3], r4 = rowv[4];
            const float A[KB] = {r0.x, r0.y, r0.z, r0.w, r1.x, r1.y, r1.z, r1.w, r2.x};
            const float C[KB] = {r2.y, r2.z, r2.w, r3.x, r3.y, r3.z, r3.w, r4.x, r4.y};
            float lg[KB];   // base-2 logits (table pre-scaled by log2e)
            #pragma unroll
            for (int k = 0; k < KB; ++k) lg[k] = fmaf(A[k], xe, C[k]);
            float m = lg[0];
            #pragma unroll
            for (int k = 1; k < KB; ++k) m = fmaxf(m, lg[k]);
            float p[KB];
            float s = 0.0f;
            #pragma unroll
            for (int k = 0; k < KB; ++k) { p[k] = exp2f(lg[k] - m); s += p[k]; }
            const float rcp = __frcp_rn(s);
            v2f* po = (v2f*)(tile + (e - ch * CHUNK) * NB);
            po[0] = (v2f){0.0f,        p[0] * rcp};
            po[1] = (v2f){p[1] * rcp,  p[2] * rcp};
            po[2] = (v2f){p[3] * rcp,  p[4] * rcp};
            po[3] = (v2f){p[5] * rcp,  p[6] * rcp};
            po[4] = (v2f){p[7] * rcp,  p[8] * rcp};
        }
        __syncthreads();             // tile scatter done

        // stream: merge defaults + tile, full-line coalesced nontemporal stores.
        // f4 g covers floats p0=4g..4g+3 of the chunk; element = p/10, pos = p%10.
        // zero element: pos0 -> 1, else 0. nonzero: tile value (scatter wrote all
        // 10 positions incl. pos0=0). Unwritten tile lanes are selected away.
        const int cb = ch * CHUNK;
        #pragma unroll
        for (int q = 0; q < (CHUNK * NB) / (4 * BLOCK); ++q) {   // 5 f4s/thread
            const int g = q * BLOCK + tid;
            const unsigned p0 = 4u * (unsigned)g;
            const unsigned ea = p0 / 10u;
            const int rb = (int)(p0 - 10u * ea);
            const int ebi = ((int)ea + 1 < CHUNK) ? (int)ea + 1 : CHUNK - 1;
            const float xva = xs[cb + (int)ea];
            const float xvb = xs[cb + ebi];
            const v4f tv = ((const v4f*)tile)[g];
            v4f res;
            #pragma unroll
            for (int j = 0; j < 4; ++j) {
                const int t = rb + j;                    // pos within (up to) 2 elems
                const float xv = (t >= 10) ? xvb : xva;
                const float dfl = (t == 0 || t == 10) ? 1.0f : 0.0f;
                res[j] = (xv != 0.0f) ? tv[j] : dfl;
            }
            __builtin_nontemporal_store(res, ((v4f*)gout) + (ch * (CHUNK * NB / 4) + g));
        }
        __syncthreads();             // tile drained before next chunk's scatter
    }
}

// ---------------- fallback if d_ws too small: self-contained, per-block table ----------------
__global__ __launch_bounds__(BLOCK) void fused_kernel(
    const float* __restrict__ expr,
    const float* __restrict__ W1, const float* __restrict__ b1,
    const float* __restrict__ W2, const float* __restrict__ b2,
    float* __restrict__ out)
{
    __shared__ float ts[128];
    __shared__ float tab[65 * RSTRIDE];
    __shared__ float st[HID], sw[HID], sb[HID], tsrt[HID];
    const int tid = threadIdx.x;
    if (tid < HID) {
        float w = W1[tid], b = b1[tid];
        st[tid] = (w != 0.0f) ? (-b / w) : -SENT;
        sw[tid] = w; sb[tid] = b;
    }
    __syncthreads();
    if (tid < HID) {
        float t = st[tid];
        int r = 0;
        for (int i = 0; i < HID; ++i) {
            float ti = st[i];
            r += (ti < t || (ti == t && i < tid)) ? 1 : 0;
        }
        tsrt[r] = t;
    }
    __syncthreads();
    if (tid < 128) ts[tid] = (tid < HID) ? tsrt[tid] : SENT;
    for (int item = tid; item < 65 * KB; item += BLOCK) {
        int r = item / KB, k = item - r * KB;
        float xm;
        if (r == 0)        xm = tsrt[0] - 1.0f;
        else if (r == HID) xm = tsrt[HID - 1] + 1.0f;
        else               xm = 0.5f * (tsrt[r - 1] + tsrt[r]);
        float A = 0.0f, C = b2[k];
        for (int j = 0; j < HID; ++j) {
            float w = sw[j], bb = sb[j];
            float s = (fmaf(w, xm, bb) >= 0.0f) ? 1.0f : LEAKY;
            float w2s = W2[j * KB + k] * s;
            A = fmaf(w2s, w, A);
            C = fmaf(w2s, bb, C);
        }
        tab[r * RSTRIDE + k] = A;
        tab[r * RSTRIDE + KB + k] = C;
    }
    __syncthreads();
    const int i0 = (blockIdx.x * BLOCK + tid) * FEPT;
    const float2 xv = *(const float2*)(expr + i0);
    float x[FEPT] = {xv.x, xv.y};
    float o[FEPT * NB]; float msk[FEPT];
    #pragma unroll
    for (int e = 0; e < FEPT; ++e) {
        const float xe = x[e];
        int idx = 0;
        #pragma unroll
        for (int s = 64; s >= 1; s >>= 1) idx += (ts[idx + s - 1] <= xe) ? s : 0;
        const float* row = tab + idx * RSTRIDE;
        float lg[KB];
        #pragma unroll
        for (int k = 0; k < KB; ++k) lg[k] = fmaf(row[k], xe, row[KB + k]);
        float m = lg[0];
        #pragma unroll
        for (int k = 1; k < KB; ++k) m = fmaxf(m, lg[k]);
        float p[KB]; float s = 0.0f;
        #pragma unroll
        for (int k = 0; k < KB; ++k) { p[k] = __expf(lg[k] - m); s += p[k]; }
        const float rcp = __frcp_rn(s);
        const bool nz = (xe != 0.0f);
        msk[e] = nz ? 1.0f : 0.0f;
        o[e * NB] = nz ? 0.0f : 1.0f;
        #pragma unroll
        for (int k = 0; k < KB; ++k) o[e * NB + 1 + k] = nz ? p[k] * rcp : 0.0f;
    }
    float* dst = out + (size_t)i0 * NB;
    #pragma unroll
    for (int q = 0; q < FEPT * NB / 4; ++q) ((float4*)dst)[q] = ((const float4*)o)[q];
    *(float2*)(out + (size_t)NTOT * NB + i0) = make_float2(msk[0], msk[1]);
}

extern "C" void kernel_launch(void* const* d_in, const int* in_sizes, int n_in,
                              void* d_out, int out_size, void* d_ws, size_t ws_size,
                              hipStream_t stream) {
    const float* expr = (const float*)d_in[0];
    const float* W1   = (const float*)d_in[1];
    const float* b1   = (const float*)d_in[2];
    const float* W2   = (const float*)d_in[3];
    const float* b2   = (const float*)d_in[4];
    float* out = (float*)d_out;

    if (ws_size >= (size_t)WS_BYTES) {
        float* ws = (float*)d_ws;
        setup_kernel<<<65 + NBUK / 64, 64, 0, stream>>>(W1, b1, W2, b2, ws);
        main_kernel<<<NTOT / EPB, BLOCK, 0, stream>>>(expr, ws, out);   // 1250 blocks
    } else {
        fused_kernel<<<NTOT / (BLOCK * FEPT), BLOCK, 0, stream>>>(expr, W1, b1, W2, b2, out);
    }
}